// Round 1
// baseline (179.014 us; speedup 1.0000x reference)
//
#include <hip/hip_runtime.h>
#include <math.h>

#define BB 8
#define NN 100
#define KK 20
#define DD 256
#define MM 2000                    // NN*KK anchors per batch
#define MP 2048                    // padded rows per batch
#define NTILE 136                  // upper-tri 128x128 tile pairs in 16x16 grid
#define GRID2 (BB * NTILE)         // 1088 blocks in the gram kernel
#define TINV 10.0f                 // 1/TEMP
#define LOSS_SCALE 1.953125e-7f    // ALPHA / (B_NORM*N*K*D) = 0.1/512000

typedef __bf16 bf16x8 __attribute__((ext_vector_type(8)));
typedef float floatx4 __attribute__((ext_vector_type(4)));
typedef __attribute__((address_space(1))) const ushort GUshort;
typedef __attribute__((address_space(3))) ushort LUshort;

__device__ __forceinline__ ushort f2bf(float f) {
    unsigned int u = __float_as_uint(f);
    u += 0x7fffu + ((u >> 16) & 1u);   // round-to-nearest-even
    return (ushort)(u >> 16);
}

// ---------------- kernel 1: normalize+convert to bf16, zero-pad, zero accumulators ----------------
__global__ void norm_bf16(const float* __restrict__ x, ushort* __restrict__ xb,
                          float* __restrict__ accbuf, unsigned int* __restrict__ ctr) {
    // fold accumulator + completion-counter zero-init into this pass (no memset dispatches)
    // accbuf covers denom_g+intra_g = 2*8*2048 floats = 128 KB = 32 blocks * 256 threads * 16 B
    if (blockIdx.x < 32)
        ((float4*)accbuf)[blockIdx.x * 256 + threadIdx.x] = make_float4(0.f, 0.f, 0.f, 0.f);
    if (blockIdx.x == 0 && threadIdx.x == 0) ctr[0] = 0u;

    const int rg = blockIdx.x * 4 + (threadIdx.x >> 6);   // 0..16383
    const int lane = threadIdx.x & 63;
    const int b = rg >> 11;
    const int r = rg & (MP - 1);
    ushort4 outv = make_ushort4(0, 0, 0, 0);
    if (r < MM) {   // wave-uniform branch
        const float4 v = ((const float4*)(x + ((size_t)(b * MM + r)) * DD))[lane];
        float s = v.x * v.x + v.y * v.y + v.z * v.z + v.w * v.w;
        #pragma unroll
        for (int o = 32; o >= 1; o >>= 1) s += __shfl_xor(s, o, 64);
        const float inv = 1.0f / sqrtf(s);
        outv.x = f2bf(v.x * inv);
        outv.y = f2bf(v.y * inv);
        outv.z = f2bf(v.z * inv);
        outv.w = f2bf(v.w * inv);
    }
    ((ushort4*)(xb + (size_t)rg * DD))[lane] = outv;
}

// ---------------- kernel 2: symmetric MFMA Gram + fused exp/intra epilogue + fused finalize ----------------
// Both A and B staged in LDS via global_load_lds(16B), granule-XOR swizzle
// (conflict-free b128 frag reads AND lane-contiguous DMA). XCD-pinned: batch = blk&7,
// so each XCD's L2 holds only its batch's 1 MB xb slice (FETCH 33->4 MB, measured R5).
// The last block to finish (device-scope ticket counter) performs the log/intra
// finalize reduction itself -> third kernel launch eliminated.
__global__ __launch_bounds__(256)
void cl_mfma(const ushort* __restrict__ xb,
             float* __restrict__ denom_g, float* __restrict__ intra_g,
             unsigned int* __restrict__ ctr, float* __restrict__ out) {
    __shared__ __align__(16) ushort As[128 * 64];
    __shared__ __align__(16) ushort Bs[128 * 64];

    // decode block -> (batch = blk&7 for XCD pinning, upper-tri tile pair)
    const int b = blockIdx.x & 7;
    int rem = blockIdx.x >> 3;    // 0..135
    int ti = 0;
    while (rem >= 16 - ti) { rem -= 16 - ti; ++ti; }
    const int tj = ti + rem;
    const int rbase = ti << 7;
    const int cbase = tj << 7;
    const bool offdiag = (ti != tj);
    const ushort* __restrict__ xbb = xb + (size_t)b * MP * DD;

    const int tid = threadIdx.x;
    const int lane = tid & 63;
    const int w = tid >> 6;
    const int wr = (w >> 1) << 6;   // wave row offset within 128-tile
    const int wc = (w & 1) << 6;    // wave col offset
    const int tx = lane & 15;
    const int tx7 = tx & 7;
    const int quad = lane >> 4;

    // staging lane roles: 8 rows x 8 granule-slots per instruction
    const int srow = lane >> 3;          // row within 8-row chunk
    const int sg = (lane & 7) ^ srow;    // logical granule this slot holds

    floatx4 acc[4][4];
    #pragma unroll
    for (int mt = 0; mt < 4; ++mt)
        #pragma unroll
        for (int nt = 0; nt < 4; ++nt)
            acc[mt][nt] = (floatx4){0.f, 0.f, 0.f, 0.f};

    #pragma unroll 1
    for (int kc = 0; kc < 4; ++kc) {
        __syncthreads();
        #pragma unroll
        for (int q = 0; q < 4; ++q) {
            const int R = ((w << 2) + q) << 3;            // 8-row chunk base
            const size_t koff = (kc << 6) + (sg << 3);
            __builtin_amdgcn_global_load_lds(
                (GUshort*)(xbb + (size_t)(rbase + R + srow) * DD + koff),
                (LUshort*)(As + R * 64), 16, 0, 0);
            __builtin_amdgcn_global_load_lds(
                (GUshort*)(xbb + (size_t)(cbase + R + srow) * DD + koff),
                (LUshort*)(Bs + R * 64), 16, 0, 0);
        }
        __syncthreads();

        #pragma unroll
        for (int ks = 0; ks < 2; ++ks) {
            const int g = (ks << 2) + quad;          // logical granule
            const int gp = (g ^ tx7) << 3;           // swizzled ushort offset
            bf16x8 af[4], bf[4];
            #pragma unroll
            for (int mt = 0; mt < 4; ++mt)
                af[mt] = *(const bf16x8*)(As + (wr + (mt << 4) + tx) * 64 + gp);
            #pragma unroll
            for (int nt = 0; nt < 4; ++nt)
                bf[nt] = *(const bf16x8*)(Bs + (wc + (nt << 4) + tx) * 64 + gp);
            #pragma unroll
            for (int mt = 0; mt < 4; ++mt)
                #pragma unroll
                for (int nt = 0; nt < 4; ++nt)
                    acc[mt][nt] = __builtin_amdgcn_mfma_f32_16x16x32_bf16(af[mt], bf[nt], acc[mt][nt], 0, 0, 0);
        }
    }

    // epilogue. C/D layout: col=lane&15, row=quad*4+reg.
    int colv[4], colcls[4];
    bool colok[4];
    #pragma unroll
    for (int nt = 0; nt < 4; ++nt) {
        const int c = cbase + wc + (nt << 4) + tx;
        colv[nt] = c;
        colok[nt] = c < MM;
        colcls[nt] = c / KK;
    }
    float de_c[4] = {0.f, 0.f, 0.f, 0.f};
    float it_c[4] = {0.f, 0.f, 0.f, 0.f};

    #pragma unroll
    for (int mt = 0; mt < 4; ++mt) {
        #pragma unroll
        for (int i = 0; i < 4; ++i) {
            const int row = rbase + wr + (mt << 4) + (quad << 2) + i;
            const int rcls = row / KK;
            float de = 0.f, it = 0.f;
            #pragma unroll
            for (int nt = 0; nt < 4; ++nt) {
                const float sim = acc[mt][nt][i] * TINV;
                const bool ok = colok[nt] && (colv[nt] != row);
                const float e = ok ? __expf(sim) : 0.0f;
                const float sv = (ok && (colcls[nt] == rcls)) ? sim : 0.0f;
                de += e;
                it += sv;
                de_c[nt] += e;   // col-side (used only when offdiag)
                it_c[nt] += sv;
            }
            #pragma unroll
            for (int o = 8; o >= 1; o >>= 1) {
                de += __shfl_xor(de, o, 64);
                it += __shfl_xor(it, o, 64);
            }
            if (tx == 0) {
                atomicAdd(&denom_g[b * MP + row], de);
                atomicAdd(&intra_g[b * MP + row], it);
            }
        }
    }

    if (offdiag) {
        #pragma unroll
        for (int nt = 0; nt < 4; ++nt) {
            de_c[nt] += __shfl_xor(de_c[nt], 16, 64);
            de_c[nt] += __shfl_xor(de_c[nt], 32, 64);
            it_c[nt] += __shfl_xor(it_c[nt], 16, 64);
            it_c[nt] += __shfl_xor(it_c[nt], 32, 64);
        }
        if (quad == 0) {
            #pragma unroll
            for (int nt = 0; nt < 4; ++nt) {
                if (colok[nt]) {
                    atomicAdd(&denom_g[b * MP + colv[nt]], de_c[nt]);
                    atomicAdd(&intra_g[b * MP + colv[nt]], it_c[nt]);
                }
            }
        }
    }

    // ---- fused finalize: last block to retire does the log/intra reduction ----
    __syncthreads();        // all epilogue atomics of this block issued & drained (vmcnt at barrier)
    __threadfence();        // device-scope release before the ticket bump
    unsigned int* tick = (unsigned int*)As;       // As is dead; reuse (keeps LDS at 32 KB -> 5 blk/CU)
    if (tid == 0) tick[0] = atomicAdd(ctr, 1u);
    __syncthreads();
    if (tick[0] == GRID2 - 1) {   // block-uniform condition
        __threadfence();          // acquire side
        float s = 0.0f;
        for (int i = tid; i < BB * MM; i += 256) {
            const int b2 = i / MM;
            const int r2 = i - b2 * MM;
            // agent-scope loads: bypass non-coherent per-XCD caches so all blocks' atomics are visible
            const float dv = __hip_atomic_load(&denom_g[b2 * MP + r2], __ATOMIC_RELAXED, __HIP_MEMORY_SCOPE_AGENT);
            const float iv = __hip_atomic_load(&intra_g[b2 * MP + r2], __ATOMIC_RELAXED, __HIP_MEMORY_SCOPE_AGENT);
            s += logf(dv) - iv * (1.0f / (KK - 1));
        }
        #pragma unroll
        for (int o = 32; o >= 1; o >>= 1) s += __shfl_xor(s, o, 64);
        float* red = (float*)(As + 128);          // disjoint from tick (byte 256 vs byte 0)
        if (lane == 0) red[w] = s;
        __syncthreads();
        if (tid == 0) out[0] = (red[0] + red[1] + red[2] + red[3]) * LOSS_SCALE;
    }
}

extern "C" void kernel_launch(void* const* d_in, const int* in_sizes, int n_in,
                              void* d_out, int out_size, void* d_ws, size_t ws_size,
                              hipStream_t stream) {
    const float* x = (const float*)d_in[0];
    float* out = (float*)d_out;
    float* denom_g = (float*)d_ws;                 // 8*2048 floats
    float* intra_g = denom_g + BB * MP;            // 8*2048 floats
    ushort* xb = (ushort*)(intra_g + BB * MP);     // 8*2048*256 bf16 = 8 MB
    unsigned int* ctr = (unsigned int*)(xb + (size_t)BB * MP * DD);  // completion counter

    norm_bf16<<<BB * MP / 4, 256, 0, stream>>>(x, xb, denom_g, ctr);
    cl_mfma<<<GRID2, 256, 0, stream>>>(xb, denom_g, intra_g, ctr, out);
}

// Round 2
// 124.510 us; speedup vs baseline: 1.4377x; 1.4377x over previous
//
#include <hip/hip_runtime.h>
#include <math.h>

#define BB 8
#define NN 100
#define KK 20
#define DD 256
#define MM 2000                    // NN*KK anchors per batch
#define MP 2048                    // padded rows per batch
#define NTILE 136                  // upper-tri 128x128 tile pairs in 16x16 grid
#define GRID2 (BB * NTILE)         // 1088 blocks in the gram kernel
#define TINV 10.0f                 // 1/TEMP
#define LOSS_SCALE 1.953125e-7f    // ALPHA / (B_NORM*N*K*D) = 0.1/512000

typedef __bf16 bf16x8 __attribute__((ext_vector_type(8)));
typedef float floatx4 __attribute__((ext_vector_type(4)));
typedef __attribute__((address_space(1))) const ushort GUshort;
typedef __attribute__((address_space(3))) ushort LUshort;

__device__ __forceinline__ ushort f2bf(float f) {
    unsigned int u = __float_as_uint(f);
    u += 0x7fffu + ((u >> 16) & 1u);   // round-to-nearest-even
    return (ushort)(u >> 16);
}

// ---------------- kernel 1: normalize+convert to bf16, zero-pad, zero accumulators ----------------
__global__ void norm_bf16(const float* __restrict__ x, ushort* __restrict__ xb,
                          float* __restrict__ accbuf, unsigned int* __restrict__ ctr) {
    // fold accumulator + completion-counter zero-init into this pass (no memset dispatches)
    // accbuf covers denom_g+intra_g = 2*8*2048 floats = 128 KB = 32 blocks * 256 threads * 16 B
    if (blockIdx.x < 32)
        ((float4*)accbuf)[blockIdx.x * 256 + threadIdx.x] = make_float4(0.f, 0.f, 0.f, 0.f);
    if (blockIdx.x == 0 && threadIdx.x == 0) ctr[0] = 0u;

    const int rg = blockIdx.x * 4 + (threadIdx.x >> 6);   // 0..16383
    const int lane = threadIdx.x & 63;
    const int b = rg >> 11;
    const int r = rg & (MP - 1);
    ushort4 outv = make_ushort4(0, 0, 0, 0);
    if (r < MM) {   // wave-uniform branch
        const float4 v = ((const float4*)(x + ((size_t)(b * MM + r)) * DD))[lane];
        float s = v.x * v.x + v.y * v.y + v.z * v.z + v.w * v.w;
        #pragma unroll
        for (int o = 32; o >= 1; o >>= 1) s += __shfl_xor(s, o, 64);
        const float inv = 1.0f / sqrtf(s);
        outv.x = f2bf(v.x * inv);
        outv.y = f2bf(v.y * inv);
        outv.z = f2bf(v.z * inv);
        outv.w = f2bf(v.w * inv);
    }
    ((ushort4*)(xb + (size_t)rg * DD))[lane] = outv;
}

// ---------------- kernel 2: symmetric MFMA Gram + fused exp/intra epilogue + fused finalize ----------------
// Both A and B staged in LDS via global_load_lds(16B), granule-XOR swizzle
// (conflict-free b128 frag reads AND lane-contiguous DMA). XCD-pinned: batch = blk&7,
// so each XCD's L2 holds only its batch's 1 MB xb slice (FETCH 33->4 MB, measured R5).
// The last block to finish (device-scope ticket counter) performs the log/intra
// finalize reduction itself -> third kernel launch eliminated.
//
// NO __threadfence() in the ticket protocol (R1 post-mortem): a per-block agent
// release fence emits an L2 writeback on gfx950 (WRITE_SIZE 0.26->10.8 MB, cl_mfma
// 20->120 us measured). It is redundant: __syncthreads() drains vmcnt(0) (all data
// atomics COMPLETED at the device coherence point, where device-scope atomicAdd is
// performed), and the reader uses agent-scope atomic loads that bypass stale caches.
__global__ __launch_bounds__(256)
void cl_mfma(const ushort* __restrict__ xb,
             float* __restrict__ denom_g, float* __restrict__ intra_g,
             unsigned int* __restrict__ ctr, float* __restrict__ out) {
    __shared__ __align__(16) ushort As[128 * 64];
    __shared__ __align__(16) ushort Bs[128 * 64];

    // decode block -> (batch = blk&7 for XCD pinning, upper-tri tile pair)
    const int b = blockIdx.x & 7;
    int rem = blockIdx.x >> 3;    // 0..135
    int ti = 0;
    while (rem >= 16 - ti) { rem -= 16 - ti; ++ti; }
    const int tj = ti + rem;
    const int rbase = ti << 7;
    const int cbase = tj << 7;
    const bool offdiag = (ti != tj);
    const ushort* __restrict__ xbb = xb + (size_t)b * MP * DD;

    const int tid = threadIdx.x;
    const int lane = tid & 63;
    const int w = tid >> 6;
    const int wr = (w >> 1) << 6;   // wave row offset within 128-tile
    const int wc = (w & 1) << 6;    // wave col offset
    const int tx = lane & 15;
    const int tx7 = tx & 7;
    const int quad = lane >> 4;

    // staging lane roles: 8 rows x 8 granule-slots per instruction
    const int srow = lane >> 3;          // row within 8-row chunk
    const int sg = (lane & 7) ^ srow;    // logical granule this slot holds

    floatx4 acc[4][4];
    #pragma unroll
    for (int mt = 0; mt < 4; ++mt)
        #pragma unroll
        for (int nt = 0; nt < 4; ++nt)
            acc[mt][nt] = (floatx4){0.f, 0.f, 0.f, 0.f};

    #pragma unroll 1
    for (int kc = 0; kc < 4; ++kc) {
        __syncthreads();
        #pragma unroll
        for (int q = 0; q < 4; ++q) {
            const int R = ((w << 2) + q) << 3;            // 8-row chunk base
            const size_t koff = (kc << 6) + (sg << 3);
            __builtin_amdgcn_global_load_lds(
                (GUshort*)(xbb + (size_t)(rbase + R + srow) * DD + koff),
                (LUshort*)(As + R * 64), 16, 0, 0);
            __builtin_amdgcn_global_load_lds(
                (GUshort*)(xbb + (size_t)(cbase + R + srow) * DD + koff),
                (LUshort*)(Bs + R * 64), 16, 0, 0);
        }
        __syncthreads();

        #pragma unroll
        for (int ks = 0; ks < 2; ++ks) {
            const int g = (ks << 2) + quad;          // logical granule
            const int gp = (g ^ tx7) << 3;           // swizzled ushort offset
            bf16x8 af[4], bf[4];
            #pragma unroll
            for (int mt = 0; mt < 4; ++mt)
                af[mt] = *(const bf16x8*)(As + (wr + (mt << 4) + tx) * 64 + gp);
            #pragma unroll
            for (int nt = 0; nt < 4; ++nt)
                bf[nt] = *(const bf16x8*)(Bs + (wc + (nt << 4) + tx) * 64 + gp);
            #pragma unroll
            for (int mt = 0; mt < 4; ++mt)
                #pragma unroll
                for (int nt = 0; nt < 4; ++nt)
                    acc[mt][nt] = __builtin_amdgcn_mfma_f32_16x16x32_bf16(af[mt], bf[nt], acc[mt][nt], 0, 0, 0);
        }
    }

    // epilogue. C/D layout: col=lane&15, row=quad*4+reg.
    int colv[4], colcls[4];
    bool colok[4];
    #pragma unroll
    for (int nt = 0; nt < 4; ++nt) {
        const int c = cbase + wc + (nt << 4) + tx;
        colv[nt] = c;
        colok[nt] = c < MM;
        colcls[nt] = c / KK;
    }
    float de_c[4] = {0.f, 0.f, 0.f, 0.f};
    float it_c[4] = {0.f, 0.f, 0.f, 0.f};

    #pragma unroll
    for (int mt = 0; mt < 4; ++mt) {
        #pragma unroll
        for (int i = 0; i < 4; ++i) {
            const int row = rbase + wr + (mt << 4) + (quad << 2) + i;
            const int rcls = row / KK;
            float de = 0.f, it = 0.f;
            #pragma unroll
            for (int nt = 0; nt < 4; ++nt) {
                const float sim = acc[mt][nt][i] * TINV;
                const bool ok = colok[nt] && (colv[nt] != row);
                const float e = ok ? __expf(sim) : 0.0f;
                const float sv = (ok && (colcls[nt] == rcls)) ? sim : 0.0f;
                de += e;
                it += sv;
                de_c[nt] += e;   // col-side (used only when offdiag)
                it_c[nt] += sv;
            }
            #pragma unroll
            for (int o = 8; o >= 1; o >>= 1) {
                de += __shfl_xor(de, o, 64);
                it += __shfl_xor(it, o, 64);
            }
            if (tx == 0) {
                atomicAdd(&denom_g[b * MP + row], de);
                atomicAdd(&intra_g[b * MP + row], it);
            }
        }
    }

    if (offdiag) {
        #pragma unroll
        for (int nt = 0; nt < 4; ++nt) {
            de_c[nt] += __shfl_xor(de_c[nt], 16, 64);
            de_c[nt] += __shfl_xor(de_c[nt], 32, 64);
            it_c[nt] += __shfl_xor(it_c[nt], 16, 64);
            it_c[nt] += __shfl_xor(it_c[nt], 32, 64);
        }
        if (quad == 0) {
            #pragma unroll
            for (int nt = 0; nt < 4; ++nt) {
                if (colok[nt]) {
                    atomicAdd(&denom_g[b * MP + colv[nt]], de_c[nt]);
                    atomicAdd(&intra_g[b * MP + colv[nt]], it_c[nt]);
                }
            }
        }
    }

    // ---- fused finalize: last block to retire does the log/intra reduction ----
    // __syncthreads() drains vmcnt(0): all this block's device-scope atomics have
    // COMPLETED at the coherence point before the ticket bump issues. No fence.
    __syncthreads();
    unsigned int* tick = (unsigned int*)As;       // As is dead; reuse (keeps LDS at 32 KB -> 5 blk/CU)
    if (tid == 0) tick[0] = atomicAdd(ctr, 1u);
    __syncthreads();
    if (tick[0] == GRID2 - 1) {   // block-uniform condition
        float s = 0.0f;
        for (int i = tid; i < BB * MM; i += 256) {
            const int b2 = i / MM;
            const int r2 = i - b2 * MM;
            // agent-scope loads: bypass non-coherent per-XCD caches so all blocks' atomics are visible
            const float dv = __hip_atomic_load(&denom_g[b2 * MP + r2], __ATOMIC_RELAXED, __HIP_MEMORY_SCOPE_AGENT);
            const float iv = __hip_atomic_load(&intra_g[b2 * MP + r2], __ATOMIC_RELAXED, __HIP_MEMORY_SCOPE_AGENT);
            s += logf(dv) - iv * (1.0f / (KK - 1));
        }
        #pragma unroll
        for (int o = 32; o >= 1; o >>= 1) s += __shfl_xor(s, o, 64);
        float* red = (float*)(As + 128);          // disjoint from tick (byte 256 vs byte 0)
        if (lane == 0) red[w] = s;
        __syncthreads();
        if (tid == 0) out[0] = (red[0] + red[1] + red[2] + red[3]) * LOSS_SCALE;
    }
}

extern "C" void kernel_launch(void* const* d_in, const int* in_sizes, int n_in,
                              void* d_out, int out_size, void* d_ws, size_t ws_size,
                              hipStream_t stream) {
    const float* x = (const float*)d_in[0];
    float* out = (float*)d_out;
    float* denom_g = (float*)d_ws;                 // 8*2048 floats
    float* intra_g = denom_g + BB * MP;            // 8*2048 floats
    ushort* xb = (ushort*)(intra_g + BB * MP);     // 8*2048*256 bf16 = 8 MB
    unsigned int* ctr = (unsigned int*)(xb + (size_t)BB * MP * DD);  // completion counter

    norm_bf16<<<BB * MP / 4, 256, 0, stream>>>(x, xb, denom_g, ctr);
    cl_mfma<<<GRID2, 256, 0, stream>>>(xb, denom_g, intra_g, ctr, out);
}

// Round 3
// 105.747 us; speedup vs baseline: 1.6928x; 1.1774x over previous
//
#include <hip/hip_runtime.h>
#include <math.h>

#define BB 8
#define NN 100
#define KK 20
#define DD 256
#define MM 2000                    // NN*KK anchors per batch
#define MP 2048                    // padded rows per batch
#define NTILE 136                  // upper-tri 128x128 tile pairs in 16x16 grid
#define GRID2 (BB * NTILE)         // 1088 blocks in the gram kernel
#define TINV 10.0f                 // 1/TEMP
#define LOSS_SCALE 1.953125e-7f    // ALPHA / (B_NORM*N*K*D) = 0.1/512000

typedef __bf16 bf16x8 __attribute__((ext_vector_type(8)));
typedef float floatx4 __attribute__((ext_vector_type(4)));
typedef __attribute__((address_space(1))) const ushort GUshort;
typedef __attribute__((address_space(3))) ushort LUshort;

__device__ __forceinline__ ushort f2bf(float f) {
    unsigned int u = __float_as_uint(f);
    u += 0x7fffu + ((u >> 16) & 1u);   // round-to-nearest-even
    return (ushort)(u >> 16);
}

// ---------------- kernel 1: normalize+convert to bf16, zero-pad, zero accumulators ----------------
__global__ void norm_bf16(const float* __restrict__ x, ushort* __restrict__ xb,
                          float* __restrict__ accbuf, unsigned int* __restrict__ ctr,
                          float* __restrict__ out) {
    // fold accumulator + per-batch ticket counters + out zero-init into this pass
    if (blockIdx.x < 32)
        ((float4*)accbuf)[blockIdx.x * 256 + threadIdx.x] = make_float4(0.f, 0.f, 0.f, 0.f);
    if (blockIdx.x == 0 && threadIdx.x < BB) ctr[threadIdx.x] = 0u;
    if (blockIdx.x == 0 && threadIdx.x == 0) out[0] = 0.0f;

    const int rg = blockIdx.x * 4 + (threadIdx.x >> 6);   // 0..16383
    const int lane = threadIdx.x & 63;
    const int b = rg >> 11;
    const int r = rg & (MP - 1);
    ushort4 outv = make_ushort4(0, 0, 0, 0);
    if (r < MM) {   // wave-uniform branch
        const float4 v = ((const float4*)(x + ((size_t)(b * MM + r)) * DD))[lane];
        float s = v.x * v.x + v.y * v.y + v.z * v.z + v.w * v.w;
        #pragma unroll
        for (int o = 32; o >= 1; o >>= 1) s += __shfl_xor(s, o, 64);
        const float inv = 1.0f / sqrtf(s);
        outv.x = f2bf(v.x * inv);
        outv.y = f2bf(v.y * inv);
        outv.z = f2bf(v.z * inv);
        outv.w = f2bf(v.w * inv);
    }
    ((ushort4*)(xb + (size_t)rg * DD))[lane] = outv;
}

// ---------------- kernel 2: symmetric MFMA Gram + fused exp/intra epilogue + fused finalize ----------------
// Both A and B staged in LDS via global_load_lds(16B), granule-XOR swizzle.
// XCD-pinned: batch = blk&7.
//
// Finalize fusion, v3 (R2 post-mortem): R2's single last-block finalize was a
// ~45 us serial tail (62 iters x ~1700cy dependent uncached loads on ONE CU after
// the whole grid drained). Fix: (a) PER-BATCH tickets -> 8 finalize blocks, each
// starting as soon as ITS 136 tiles drain (overlaps other batches' main bodies);
// (b) ILP-batch the agent-scope loads: 16 independent loads into statically-indexed
// regs first, then the logf math -> HBM latency paid once, not 8x.
// No __threadfence (R1 post-mortem: per-block agent fence = L2 writeback storm);
// __syncthreads drains vmcnt(0) so this block's device-scope atomics COMPLETED
// before the ticket bump; readers use agent-scope atomic loads (bypass stale L2).
__global__ __launch_bounds__(256)
void cl_mfma(const ushort* __restrict__ xb,
             float* __restrict__ denom_g, float* __restrict__ intra_g,
             unsigned int* __restrict__ ctr, float* __restrict__ out) {
    __shared__ __align__(16) ushort As[128 * 64];
    __shared__ __align__(16) ushort Bs[128 * 64];

    // decode block -> (batch = blk&7 for XCD pinning, upper-tri tile pair)
    const int b = blockIdx.x & 7;
    int rem = blockIdx.x >> 3;    // 0..135
    int ti = 0;
    while (rem >= 16 - ti) { rem -= 16 - ti; ++ti; }
    const int tj = ti + rem;
    const int rbase = ti << 7;
    const int cbase = tj << 7;
    const bool offdiag = (ti != tj);
    const ushort* __restrict__ xbb = xb + (size_t)b * MP * DD;

    const int tid = threadIdx.x;
    const int lane = tid & 63;
    const int w = tid >> 6;
    const int wr = (w >> 1) << 6;   // wave row offset within 128-tile
    const int wc = (w & 1) << 6;    // wave col offset
    const int tx = lane & 15;
    const int tx7 = tx & 7;
    const int quad = lane >> 4;

    // staging lane roles: 8 rows x 8 granule-slots per instruction
    const int srow = lane >> 3;          // row within 8-row chunk
    const int sg = (lane & 7) ^ srow;    // logical granule this slot holds

    floatx4 acc[4][4];
    #pragma unroll
    for (int mt = 0; mt < 4; ++mt)
        #pragma unroll
        for (int nt = 0; nt < 4; ++nt)
            acc[mt][nt] = (floatx4){0.f, 0.f, 0.f, 0.f};

    #pragma unroll 1
    for (int kc = 0; kc < 4; ++kc) {
        __syncthreads();
        #pragma unroll
        for (int q = 0; q < 4; ++q) {
            const int R = ((w << 2) + q) << 3;            // 8-row chunk base
            const size_t koff = (kc << 6) + (sg << 3);
            __builtin_amdgcn_global_load_lds(
                (GUshort*)(xbb + (size_t)(rbase + R + srow) * DD + koff),
                (LUshort*)(As + R * 64), 16, 0, 0);
            __builtin_amdgcn_global_load_lds(
                (GUshort*)(xbb + (size_t)(cbase + R + srow) * DD + koff),
                (LUshort*)(Bs + R * 64), 16, 0, 0);
        }
        __syncthreads();

        #pragma unroll
        for (int ks = 0; ks < 2; ++ks) {
            const int g = (ks << 2) + quad;          // logical granule
            const int gp = (g ^ tx7) << 3;           // swizzled ushort offset
            bf16x8 af[4], bf[4];
            #pragma unroll
            for (int mt = 0; mt < 4; ++mt)
                af[mt] = *(const bf16x8*)(As + (wr + (mt << 4) + tx) * 64 + gp);
            #pragma unroll
            for (int nt = 0; nt < 4; ++nt)
                bf[nt] = *(const bf16x8*)(Bs + (wc + (nt << 4) + tx) * 64 + gp);
            #pragma unroll
            for (int mt = 0; mt < 4; ++mt)
                #pragma unroll
                for (int nt = 0; nt < 4; ++nt)
                    acc[mt][nt] = __builtin_amdgcn_mfma_f32_16x16x32_bf16(af[mt], bf[nt], acc[mt][nt], 0, 0, 0);
        }
    }

    // epilogue. C/D layout: col=lane&15, row=quad*4+reg.
    int colv[4], colcls[4];
    bool colok[4];
    #pragma unroll
    for (int nt = 0; nt < 4; ++nt) {
        const int c = cbase + wc + (nt << 4) + tx;
        colv[nt] = c;
        colok[nt] = c < MM;
        colcls[nt] = c / KK;
    }
    float de_c[4] = {0.f, 0.f, 0.f, 0.f};
    float it_c[4] = {0.f, 0.f, 0.f, 0.f};

    #pragma unroll
    for (int mt = 0; mt < 4; ++mt) {
        #pragma unroll
        for (int i = 0; i < 4; ++i) {
            const int row = rbase + wr + (mt << 4) + (quad << 2) + i;
            const int rcls = row / KK;
            float de = 0.f, it = 0.f;
            #pragma unroll
            for (int nt = 0; nt < 4; ++nt) {
                const float sim = acc[mt][nt][i] * TINV;
                const bool ok = colok[nt] && (colv[nt] != row);
                const float e = ok ? __expf(sim) : 0.0f;
                const float sv = (ok && (colcls[nt] == rcls)) ? sim : 0.0f;
                de += e;
                it += sv;
                de_c[nt] += e;   // col-side (used only when offdiag)
                it_c[nt] += sv;
            }
            #pragma unroll
            for (int o = 8; o >= 1; o >>= 1) {
                de += __shfl_xor(de, o, 64);
                it += __shfl_xor(it, o, 64);
            }
            if (tx == 0) {
                atomicAdd(&denom_g[b * MP + row], de);
                atomicAdd(&intra_g[b * MP + row], it);
            }
        }
    }

    if (offdiag) {
        #pragma unroll
        for (int nt = 0; nt < 4; ++nt) {
            de_c[nt] += __shfl_xor(de_c[nt], 16, 64);
            de_c[nt] += __shfl_xor(de_c[nt], 32, 64);
            it_c[nt] += __shfl_xor(it_c[nt], 16, 64);
            it_c[nt] += __shfl_xor(it_c[nt], 32, 64);
        }
        if (quad == 0) {
            #pragma unroll
            for (int nt = 0; nt < 4; ++nt) {
                if (colok[nt]) {
                    atomicAdd(&denom_g[b * MP + colv[nt]], de_c[nt]);
                    atomicAdd(&intra_g[b * MP + colv[nt]], it_c[nt]);
                }
            }
        }
    }

    // ---- fused finalize: last block of THIS BATCH reduces its 2000 rows ----
    __syncthreads();   // drains vmcnt(0): all data atomics of this block completed
    unsigned int* tick = (unsigned int*)As;       // As is dead; reuse
    if (tid == 0) tick[0] = atomicAdd(&ctr[b], 1u);
    __syncthreads();
    if (tick[0] == NTILE - 1) {   // block-uniform: last block of batch b
        const float* dg = denom_g + b * MP;
        const float* ig = intra_g + b * MP;
        // phase 1: issue all 16 independent uncached loads into static regs
        float dv[8], iv[8];
        #pragma unroll
        for (int k = 0; k < 8; ++k) {
            const int r2 = tid + (k << 8);               // tid + k*256
            const int rc = (r2 < MM) ? r2 : 0;           // clamp (masked below)
            dv[k] = __hip_atomic_load(&dg[rc], __ATOMIC_RELAXED, __HIP_MEMORY_SCOPE_AGENT);
            iv[k] = __hip_atomic_load(&ig[rc], __ATOMIC_RELAXED, __HIP_MEMORY_SCOPE_AGENT);
        }
        // phase 2: math
        float s = 0.0f;
        #pragma unroll
        for (int k = 0; k < 8; ++k) {
            const int r2 = tid + (k << 8);
            const float t = logf(dv[k]) - iv[k] * (1.0f / (KK - 1));
            s += (r2 < MM) ? t : 0.0f;
        }
        #pragma unroll
        for (int o = 32; o >= 1; o >>= 1) s += __shfl_xor(s, o, 64);
        float* red = (float*)(As + 128);          // disjoint from tick (byte 256 vs byte 0)
        if (lane == 0) red[w] = s;
        __syncthreads();
        if (tid == 0)
            atomicAdd(out, (red[0] + red[1] + red[2] + red[3]) * LOSS_SCALE);
    }
}

extern "C" void kernel_launch(void* const* d_in, const int* in_sizes, int n_in,
                              void* d_out, int out_size, void* d_ws, size_t ws_size,
                              hipStream_t stream) {
    const float* x = (const float*)d_in[0];
    float* out = (float*)d_out;
    float* denom_g = (float*)d_ws;                 // 8*2048 floats
    float* intra_g = denom_g + BB * MP;            // 8*2048 floats
    ushort* xb = (ushort*)(intra_g + BB * MP);     // 8*2048*256 bf16 = 8 MB
    unsigned int* ctr = (unsigned int*)(xb + (size_t)BB * MP * DD);  // per-batch tickets [8]

    norm_bf16<<<BB * MP / 4, 256, 0, stream>>>(x, xb, denom_g, ctr, out);
    cl_mfma<<<GRID2, 256, 0, stream>>>(xb, denom_g, intra_g, ctr, out);
}

// Round 4
// 103.500 us; speedup vs baseline: 1.7296x; 1.0217x over previous
//
#include <hip/hip_runtime.h>
#include <math.h>

#define BB 8
#define NN 100
#define KK 20
#define DD 256
#define MM 2000                    // NN*KK anchors per batch
#define MP 2048                    // padded rows per batch
#define NTILE 136                  // upper-tri 128x128 tile pairs in 16x16 grid
#define GRID2 (BB * NTILE)         // 1088 blocks in the gram kernel
#define NSLICE 32                  // privatized reduction slices (16 tile-cols x 2 halves)
#define TINV 10.0f                 // 1/TEMP
#define LOSS_SCALE 1.953125e-7f    // ALPHA / (B_NORM*N*K*D) = 0.1/512000

typedef __bf16 bf16x8 __attribute__((ext_vector_type(8)));
typedef float floatx4 __attribute__((ext_vector_type(4)));
typedef __attribute__((address_space(1))) const ushort GUshort;
typedef __attribute__((address_space(3))) ushort LUshort;

__device__ __forceinline__ ushort f2bf(float f) {
    unsigned int u = __float_as_uint(f);
    u += 0x7fffu + ((u >> 16) & 1u);   // round-to-nearest-even
    return (ushort)(u >> 16);
}

__device__ __forceinline__ void agent_store(float* p, float v) {
    __hip_atomic_store(p, v, __ATOMIC_RELAXED, __HIP_MEMORY_SCOPE_AGENT);
}
__device__ __forceinline__ float agent_load(const float* p) {
    return __hip_atomic_load(p, __ATOMIC_RELAXED, __HIP_MEMORY_SCOPE_AGENT);
}

// ---------------- kernel 1: normalize+convert to bf16, zero-pad ----------------
// No accumulator zero-init anymore: every [slice][b][row] reduction slot has exactly
// one writer by construction (write-once privatization), so nothing to clear except
// the 8 ticket counters and out[0].
__global__ void norm_bf16(const float* __restrict__ x, ushort* __restrict__ xb,
                          unsigned int* __restrict__ ctr, float* __restrict__ out) {
    if (blockIdx.x == 0 && threadIdx.x < BB) ctr[threadIdx.x * 16] = 0u;
    if (blockIdx.x == 0 && threadIdx.x == 0) out[0] = 0.0f;

    const int rg = blockIdx.x * 4 + (threadIdx.x >> 6);   // 0..16383
    const int lane = threadIdx.x & 63;
    const int b = rg >> 11;
    const int r = rg & (MP - 1);
    ushort4 outv = make_ushort4(0, 0, 0, 0);
    if (r < MM) {   // wave-uniform branch
        const float4 v = ((const float4*)(x + ((size_t)(b * MM + r)) * DD))[lane];
        float s = v.x * v.x + v.y * v.y + v.z * v.z + v.w * v.w;
        #pragma unroll
        for (int o = 32; o >= 1; o >>= 1) s += __shfl_xor(s, o, 64);
        const float inv = 1.0f / sqrtf(s);
        outv.x = f2bf(v.x * inv);
        outv.y = f2bf(v.y * inv);
        outv.z = f2bf(v.z * inv);
        outv.w = f2bf(v.w * inv);
    }
    ((ushort4*)(xb + (size_t)rg * DD))[lane] = outv;
}

// ---------------- kernel 2: symmetric MFMA Gram + write-once slice epilogue + fused finalize ----------------
// R3 post-mortem: the ~40us body was theorized to be the ~700K device-scope f32
// atomicAdd RMWs (WRITE_SIZE 10.57MB = 660K x 16B accounting; ~340 RMWs/line bursts
// serialize at the cross-XCD coherence point; R1's fence +52us showed this pipeline
// is serialization-fragile). Fix: privatized write-once slices.
//   row-side of block (ti,tj), wave w  -> slice 2*tj+(w&1)   (col-half split)
//   col-side of block (ti,tj), wave w  -> slice 2*ti+(w>>1)  (row-half split)
// Upper-tri cover => every [slice][b][row] written by EXACTLY one wave (no zero-init,
// no RMW). Stores are relaxed agent-scope atomic stores (write-through, no return).
// Finalize (last block per batch, per-line-spread tickets) sums 32 slices/row with
// coalesced agent loads. Atomic RMWs: 700K -> 1088 tickets + 8 out-adds.
__global__ __launch_bounds__(256)
void cl_mfma(const ushort* __restrict__ xb,
             float* __restrict__ deS, float* __restrict__ itS,
             unsigned int* __restrict__ ctr, float* __restrict__ out) {
    __shared__ __align__(16) ushort As[128 * 64];
    __shared__ __align__(16) ushort Bs[128 * 64];

    // decode block -> (batch = blk&7 for XCD pinning, upper-tri tile pair)
    const int b = blockIdx.x & 7;
    int rem = blockIdx.x >> 3;    // 0..135
    int ti = 0;
    while (rem >= 16 - ti) { rem -= 16 - ti; ++ti; }
    const int tj = ti + rem;
    const int rbase = ti << 7;
    const int cbase = tj << 7;
    const bool offdiag = (ti != tj);
    const ushort* __restrict__ xbb = xb + (size_t)b * MP * DD;

    const int tid = threadIdx.x;
    const int lane = tid & 63;
    const int w = tid >> 6;
    const int wr = (w >> 1) << 6;   // wave row offset within 128-tile
    const int wc = (w & 1) << 6;    // wave col offset
    const int tx = lane & 15;
    const int tx7 = tx & 7;
    const int quad = lane >> 4;

    // staging lane roles: 8 rows x 8 granule-slots per instruction
    const int srow = lane >> 3;          // row within 8-row chunk
    const int sg = (lane & 7) ^ srow;    // logical granule this slot holds

    floatx4 acc[4][4];
    #pragma unroll
    for (int mt = 0; mt < 4; ++mt)
        #pragma unroll
        for (int nt = 0; nt < 4; ++nt)
            acc[mt][nt] = (floatx4){0.f, 0.f, 0.f, 0.f};

    #pragma unroll 1
    for (int kc = 0; kc < 4; ++kc) {
        __syncthreads();
        #pragma unroll
        for (int q = 0; q < 4; ++q) {
            const int R = ((w << 2) + q) << 3;            // 8-row chunk base
            const size_t koff = (kc << 6) + (sg << 3);
            __builtin_amdgcn_global_load_lds(
                (GUshort*)(xbb + (size_t)(rbase + R + srow) * DD + koff),
                (LUshort*)(As + R * 64), 16, 0, 0);
            __builtin_amdgcn_global_load_lds(
                (GUshort*)(xbb + (size_t)(cbase + R + srow) * DD + koff),
                (LUshort*)(Bs + R * 64), 16, 0, 0);
        }
        __syncthreads();

        #pragma unroll
        for (int ks = 0; ks < 2; ++ks) {
            const int g = (ks << 2) + quad;          // logical granule
            const int gp = (g ^ tx7) << 3;           // swizzled ushort offset
            bf16x8 af[4], bf[4];
            #pragma unroll
            for (int mt = 0; mt < 4; ++mt)
                af[mt] = *(const bf16x8*)(As + (wr + (mt << 4) + tx) * 64 + gp);
            #pragma unroll
            for (int nt = 0; nt < 4; ++nt)
                bf[nt] = *(const bf16x8*)(Bs + (wc + (nt << 4) + tx) * 64 + gp);
            #pragma unroll
            for (int mt = 0; mt < 4; ++mt)
                #pragma unroll
                for (int nt = 0; nt < 4; ++nt)
                    acc[mt][nt] = __builtin_amdgcn_mfma_f32_16x16x32_bf16(af[mt], bf[nt], acc[mt][nt], 0, 0, 0);
        }
    }

    // epilogue. C/D layout: col=lane&15, row=quad*4+reg.
    int colv[4], colcls[4];
    bool colok[4];
    #pragma unroll
    for (int nt = 0; nt < 4; ++nt) {
        const int c = cbase + wc + (nt << 4) + tx;
        colv[nt] = c;
        colok[nt] = c < MM;
        colcls[nt] = c / KK;
    }
    float de_c[4] = {0.f, 0.f, 0.f, 0.f};
    float it_c[4] = {0.f, 0.f, 0.f, 0.f};

    // write-once slice bases (unique writer per [slice][b][row] slot)
    float* __restrict__ deR = deS + ((size_t)(((tj << 1) | (w & 1)) * BB + b)) * MP;
    float* __restrict__ itR = itS + ((size_t)(((tj << 1) | (w & 1)) * BB + b)) * MP;
    float* __restrict__ deC = deS + ((size_t)(((ti << 1) | (w >> 1)) * BB + b)) * MP;
    float* __restrict__ itC = itS + ((size_t)(((ti << 1) | (w >> 1)) * BB + b)) * MP;

    #pragma unroll
    for (int mt = 0; mt < 4; ++mt) {
        #pragma unroll
        for (int i = 0; i < 4; ++i) {
            const int row = rbase + wr + (mt << 4) + (quad << 2) + i;
            const int rcls = row / KK;
            float de = 0.f, it = 0.f;
            #pragma unroll
            for (int nt = 0; nt < 4; ++nt) {
                const float sim = acc[mt][nt][i] * TINV;
                const bool ok = colok[nt] && (colv[nt] != row);
                const float e = ok ? __expf(sim) : 0.0f;
                const float sv = (ok && (colcls[nt] == rcls)) ? sim : 0.0f;
                de += e;
                it += sv;
                de_c[nt] += e;   // col-side (used only when offdiag)
                it_c[nt] += sv;
            }
            #pragma unroll
            for (int o = 8; o >= 1; o >>= 1) {
                de += __shfl_xor(de, o, 64);
                it += __shfl_xor(it, o, 64);
            }
            if (tx == 0) {
                agent_store(&deR[row], de);   // plain write-through store, no RMW
                agent_store(&itR[row], it);
            }
        }
    }

    if (offdiag) {
        #pragma unroll
        for (int nt = 0; nt < 4; ++nt) {
            de_c[nt] += __shfl_xor(de_c[nt], 16, 64);
            de_c[nt] += __shfl_xor(de_c[nt], 32, 64);
            it_c[nt] += __shfl_xor(it_c[nt], 16, 64);
            it_c[nt] += __shfl_xor(it_c[nt], 32, 64);
        }
        if (quad == 0) {
            #pragma unroll
            for (int nt = 0; nt < 4; ++nt) {
                agent_store(&deC[colv[nt]], de_c[nt]);   // rows>=MM never read; store unconditionally
                agent_store(&itC[colv[nt]], it_c[nt]);
            }
        }
    }

    // ---- fused finalize: last block of THIS BATCH reduces its 2000 rows ----
    __syncthreads();   // drains vmcnt(0): all this block's agent stores completed
    unsigned int* tick = (unsigned int*)As;       // As is dead; reuse
    if (tid == 0) tick[0] = atomicAdd(&ctr[b * 16], 1u);   // tickets on separate cache lines
    __syncthreads();
    if (tick[0] == NTILE - 1) {   // block-uniform: last block of batch b
        float s = 0.0f;
        #pragma unroll 1
        for (int k = 0; k < 8; ++k) {
            const int r2 = tid + (k << 8);               // 0..2047, always in-bounds
            float dsum = 0.0f, isum = 0.0f;
            #pragma unroll
            for (int sl = 0; sl < NSLICE; ++sl) {
                dsum += agent_load(deS + ((size_t)(sl * BB + b)) * MP + r2);   // coalesced across lanes
                isum += agent_load(itS + ((size_t)(sl * BB + b)) * MP + r2);
            }
            const float t = logf(dsum) - isum * (1.0f / (KK - 1));
            s += (r2 < MM) ? t : 0.0f;
        }
        #pragma unroll
        for (int o = 32; o >= 1; o >>= 1) s += __shfl_xor(s, o, 64);
        float* red = (float*)(As + 128);          // disjoint from tick (byte 256 vs byte 0)
        if (lane == 0) red[w] = s;
        __syncthreads();
        if (tid == 0)
            atomicAdd(out, (red[0] + red[1] + red[2] + red[3]) * LOSS_SCALE);
    }
}

extern "C" void kernel_launch(void* const* d_in, const int* in_sizes, int n_in,
                              void* d_out, int out_size, void* d_ws, size_t ws_size,
                              hipStream_t stream) {
    const float* x = (const float*)d_in[0];
    float* out = (float*)d_out;
    float* deS = (float*)d_ws;                     // 32*8*2048 floats = 2 MB
    float* itS = deS + NSLICE * BB * MP;           // 2 MB
    ushort* xb = (ushort*)(itS + NSLICE * BB * MP);// 8*2048*256 bf16 = 8 MB
    unsigned int* ctr = (unsigned int*)(xb + (size_t)BB * MP * DD);  // 8 tickets, 64B apart

    norm_bf16<<<BB * MP / 4, 256, 0, stream>>>(x, xb, ctr, out);
    cl_mfma<<<GRID2, 256, 0, stream>>>(xb, deS, itS, ctr, out);
}

// Round 6
// 100.489 us; speedup vs baseline: 1.7814x; 1.0300x over previous
//
#include <hip/hip_runtime.h>
#include <math.h>

#define BB 8
#define NN 100
#define KK 20
#define DD 256
#define MM 2000                    // NN*KK anchors per batch
#define MP 2048                    // padded rows per batch
#define NTILE 136                  // upper-tri 128x128 tile pairs in 16x16 grid
#define GRID2 (BB * NTILE)         // 1088 blocks in the gram kernel
#define NSLICE 32                  // privatized reduction slices (16 tile-cols x 2 halves)
#define TINV 10.0f                 // 1/TEMP
#define LOSS_SCALE 1.953125e-7f    // ALPHA / (B_NORM*N*K*D) = 0.1/512000

typedef __bf16 bf16x8 __attribute__((ext_vector_type(8)));
typedef float floatx4 __attribute__((ext_vector_type(4)));
typedef __attribute__((address_space(1))) const ushort GUshort;
typedef __attribute__((address_space(3))) ushort LUshort;

__device__ __forceinline__ ushort f2bf(float f) {
    unsigned int u = __float_as_uint(f);
    u += 0x7fffu + ((u >> 16) & 1u);   // round-to-nearest-even
    return (ushort)(u >> 16);
}

__device__ __forceinline__ void agent_store(float* p, float v) {
    __hip_atomic_store(p, v, __ATOMIC_RELAXED, __HIP_MEMORY_SCOPE_AGENT);
}
__device__ __forceinline__ float agent_load(const float* p) {
    return __hip_atomic_load(p, __ATOMIC_RELAXED, __HIP_MEMORY_SCOPE_AGENT);
}

// ---------------- kernel 1: normalize+convert to bf16, zero-pad ----------------
__global__ void norm_bf16(const float* __restrict__ x, ushort* __restrict__ xb,
                          unsigned int* __restrict__ ctr, float* __restrict__ out) {
    if (blockIdx.x == 0 && threadIdx.x < BB) ctr[threadIdx.x * 16] = 0u;
    if (blockIdx.x == 0 && threadIdx.x == 0) out[0] = 0.0f;

    const int rg = blockIdx.x * 4 + (threadIdx.x >> 6);   // 0..16383
    const int lane = threadIdx.x & 63;
    const int b = rg >> 11;
    const int r = rg & (MP - 1);
    ushort4 outv = make_ushort4(0, 0, 0, 0);
    if (r < MM) {   // wave-uniform branch
        const float4 v = ((const float4*)(x + ((size_t)(b * MM + r)) * DD))[lane];
        float s = v.x * v.x + v.y * v.y + v.z * v.z + v.w * v.w;
        #pragma unroll
        for (int o = 32; o >= 1; o >>= 1) s += __shfl_xor(s, o, 64);
        const float inv = 1.0f / sqrtf(s);
        outv.x = f2bf(v.x * inv);
        outv.y = f2bf(v.y * inv);
        outv.z = f2bf(v.z * inv);
        outv.w = f2bf(v.w * inv);
    }
    ((ushort4*)(xb + (size_t)rg * DD))[lane] = outv;
}

// ---------------- kernel 2: MFMA Gram, double-buffered BK=32 pipeline ----------------
// RESUBMISSION of R5 (container failed twice -> attributed to infra flake; kernel
// re-audited for LDS races / OOB / divergent barriers / swizzle bijectivity, clean).
//
// R4 post-mortem: body is latency-bound on the per-chunk vmcnt(0) drain before
// s_barrier (zero staging/compute overlap, ~4 blocks/CU TLP). Fix = T3-minimal
// 2-phase: double-buffer K in 32-col chunks inside the SAME 32KB LDS (occupancy
// unchanged), issue next-chunk global_load_lds BEFORE computing current chunk, one
// barrier per step -> DMA latency hides under ds_read+MFMA.
// Swizzle for 64B rows: slot s of row r holds granule s ^ ((r>>1)&3); staging stays
// lane-contiguous (4-lane groups cover one row's 64B), reads are a bijection onto
// contiguous 1KB (conflict-free).
// Epilogue: write-once privatized slices (R4), per-batch tickets, fused finalize.
__global__ __launch_bounds__(256)
void cl_mfma(const ushort* __restrict__ xb,
             float* __restrict__ deS, float* __restrict__ itS,
             unsigned int* __restrict__ ctr, float* __restrict__ out) {
    __shared__ __align__(16) ushort As[2][128 * 32];   // 2 x 8 KB
    __shared__ __align__(16) ushort Bs[2][128 * 32];   // 2 x 8 KB

    // decode block -> (batch = blk&7 for XCD pinning, upper-tri tile pair)
    const int b = blockIdx.x & 7;
    int rem = blockIdx.x >> 3;    // 0..135
    int ti = 0;
    while (rem >= 16 - ti) { rem -= 16 - ti; ++ti; }
    const int tj = ti + rem;
    const int rbase = ti << 7;
    const int cbase = tj << 7;
    const bool offdiag = (ti != tj);
    const ushort* __restrict__ xbb = xb + (size_t)b * MP * DD;

    const int tid = threadIdx.x;
    const int lane = tid & 63;
    const int w = tid >> 6;
    const int wr = (w >> 1) << 6;   // wave row offset within 128-tile
    const int wc = (w & 1) << 6;    // wave col offset
    const int tx = lane & 15;
    const int quad = lane >> 4;

    // staging lane roles (16 rows x 4 slots per instruction, 64B rows)
    const int srow4 = lane >> 2;                 // row within 16-row chunk
    const int slot4 = lane & 3;                  // LDS slot this lane fills
    const int sg4 = slot4 ^ ((lane >> 3) & 3);   // logical granule = slot ^ ((row>>1)&3)

    // fragment-read slot (constant across steps/mt: rows differ by multiples of 16)
    const int slot8 = (quad ^ ((tx >> 1) & 3)) << 3;   // ushort offset of 16B slot

    floatx4 acc[4][4];
    #pragma unroll
    for (int mt = 0; mt < 4; ++mt)
        #pragma unroll
        for (int nt = 0; nt < 4; ++nt)
            acc[mt][nt] = (floatx4){0.f, 0.f, 0.f, 0.f};

#define STAGE(P, T)                                                                  \
    {                                                                                \
        _Pragma("unroll")                                                            \
        for (int h = 0; h < 2; ++h) {                                                \
            const int R = (w << 5) + (h << 4);                                       \
            const size_t koff = ((size_t)(T) << 5) + (sg4 << 3);                     \
            __builtin_amdgcn_global_load_lds(                                        \
                (GUshort*)(xbb + (size_t)(rbase + R + srow4) * DD + koff),           \
                (LUshort*)(&As[P][R * 32]), 16, 0, 0);                               \
            __builtin_amdgcn_global_load_lds(                                        \
                (GUshort*)(xbb + (size_t)(cbase + R + srow4) * DD + koff),           \
                (LUshort*)(&Bs[P][R * 32]), 16, 0, 0);                               \
        }                                                                            \
    }

#define COMPUTE(P)                                                                   \
    {                                                                                \
        bf16x8 af[4], bf[4];                                                         \
        _Pragma("unroll")                                                            \
        for (int mt = 0; mt < 4; ++mt)                                               \
            af[mt] = *(const bf16x8*)(&As[P][(wr + (mt << 4) + tx) * 32 + slot8]);   \
        _Pragma("unroll")                                                            \
        for (int nt = 0; nt < 4; ++nt)                                               \
            bf[nt] = *(const bf16x8*)(&Bs[P][(wc + (nt << 4) + tx) * 32 + slot8]);   \
        _Pragma("unroll")                                                            \
        for (int mt = 0; mt < 4; ++mt)                                               \
            _Pragma("unroll")                                                        \
            for (int nt = 0; nt < 4; ++nt)                                           \
                acc[mt][nt] = __builtin_amdgcn_mfma_f32_16x16x32_bf16(               \
                    af[mt], bf[nt], acc[mt][nt], 0, 0, 0);                           \
    }

    // pipeline: stage(t+1) issued BEFORE compute(t); barrier drain finds DMA landed.
    // Safety: each __syncthreads() waits vmcnt(0)+lgkmcnt(0) per wave, so (a) the
    // prefetch DMA has landed before the COMPUTE that reads it, and (b) all waves'
    // ds_reads of a buffer are complete before any wave's next STAGE overwrites it.
    STAGE(0, 0);
    __syncthreads();
    STAGE(1, 1); COMPUTE(0); __syncthreads();
    STAGE(0, 2); COMPUTE(1); __syncthreads();
    STAGE(1, 3); COMPUTE(0); __syncthreads();
    STAGE(0, 4); COMPUTE(1); __syncthreads();
    STAGE(1, 5); COMPUTE(0); __syncthreads();
    STAGE(0, 6); COMPUTE(1); __syncthreads();
    STAGE(1, 7); COMPUTE(0); __syncthreads();
    COMPUTE(1);

#undef STAGE
#undef COMPUTE

    // epilogue. C/D layout: col=lane&15, row=quad*4+reg.
    int colv[4], colcls[4];
    bool colok[4];
    #pragma unroll
    for (int nt = 0; nt < 4; ++nt) {
        const int c = cbase + wc + (nt << 4) + tx;
        colv[nt] = c;
        colok[nt] = c < MM;
        colcls[nt] = c / KK;
    }
    float de_c[4] = {0.f, 0.f, 0.f, 0.f};
    float it_c[4] = {0.f, 0.f, 0.f, 0.f};

    // write-once slice bases (unique writer per [slice][b][row] slot)
    float* __restrict__ deR = deS + ((size_t)(((tj << 1) | (w & 1)) * BB + b)) * MP;
    float* __restrict__ itR = itS + ((size_t)(((tj << 1) | (w & 1)) * BB + b)) * MP;
    float* __restrict__ deC = deS + ((size_t)(((ti << 1) | (w >> 1)) * BB + b)) * MP;
    float* __restrict__ itC = itS + ((size_t)(((ti << 1) | (w >> 1)) * BB + b)) * MP;

    #pragma unroll
    for (int mt = 0; mt < 4; ++mt) {
        #pragma unroll
        for (int i = 0; i < 4; ++i) {
            const int row = rbase + wr + (mt << 4) + (quad << 2) + i;
            const int rcls = row / KK;
            float de = 0.f, it = 0.f;
            #pragma unroll
            for (int nt = 0; nt < 4; ++nt) {
                const float sim = acc[mt][nt][i] * TINV;
                const bool ok = colok[nt] && (colv[nt] != row);
                const float e = ok ? __expf(sim) : 0.0f;
                const float sv = (ok && (colcls[nt] == rcls)) ? sim : 0.0f;
                de += e;
                it += sv;
                de_c[nt] += e;   // col-side (used only when offdiag)
                it_c[nt] += sv;
            }
            #pragma unroll
            for (int o = 8; o >= 1; o >>= 1) {
                de += __shfl_xor(de, o, 64);
                it += __shfl_xor(it, o, 64);
            }
            if (tx == 0) {
                agent_store(&deR[row], de);   // plain write-through store, no RMW
                agent_store(&itR[row], it);
            }
        }
    }

    if (offdiag) {
        #pragma unroll
        for (int nt = 0; nt < 4; ++nt) {
            de_c[nt] += __shfl_xor(de_c[nt], 16, 64);
            de_c[nt] += __shfl_xor(de_c[nt], 32, 64);
            it_c[nt] += __shfl_xor(it_c[nt], 16, 64);
            it_c[nt] += __shfl_xor(it_c[nt], 32, 64);
        }
        if (quad == 0) {
            #pragma unroll
            for (int nt = 0; nt < 4; ++nt) {
                agent_store(&deC[colv[nt]], de_c[nt]);   // rows>=MM never read
                agent_store(&itC[colv[nt]], it_c[nt]);
            }
        }
    }

    // ---- fused finalize: last block of THIS BATCH reduces its 2000 rows ----
    __syncthreads();   // drains vmcnt(0): all this block's agent stores completed
    unsigned int* tick = (unsigned int*)&As[0][0];   // LDS dead; reuse
    if (tid == 0) tick[0] = atomicAdd(&ctr[b * 16], 1u);   // tickets on separate lines
    __syncthreads();
    if (tick[0] == NTILE - 1) {   // block-uniform: last block of batch b
        float s = 0.0f;
        #pragma unroll 1
        for (int k = 0; k < 8; ++k) {
            const int r2 = tid + (k << 8);               // 0..2047, always in-bounds
            float dsum = 0.0f, isum = 0.0f;
            #pragma unroll
            for (int sl = 0; sl < NSLICE; ++sl) {
                dsum += agent_load(deS + ((size_t)(sl * BB + b)) * MP + r2);
                isum += agent_load(itS + ((size_t)(sl * BB + b)) * MP + r2);
            }
            const float t = logf(dsum) - isum * (1.0f / (KK - 1));
            s += (r2 < MM) ? t : 0.0f;
        }
        #pragma unroll
        for (int o = 32; o >= 1; o >>= 1) s += __shfl_xor(s, o, 64);
        float* red = (float*)(&As[0][128]);          // disjoint from tick
        if (lane == 0) red[w] = s;
        __syncthreads();
        if (tid == 0)
            atomicAdd(out, (red[0] + red[1] + red[2] + red[3]) * LOSS_SCALE);
    }
}

extern "C" void kernel_launch(void* const* d_in, const int* in_sizes, int n_in,
                              void* d_out, int out_size, void* d_ws, size_t ws_size,
                              hipStream_t stream) {
    const float* x = (const float*)d_in[0];
    float* out = (float*)d_out;
    float* deS = (float*)d_ws;                     // 32*8*2048 floats = 2 MB
    float* itS = deS + NSLICE * BB * MP;           // 2 MB
    ushort* xb = (ushort*)(itS + NSLICE * BB * MP);// 8*2048*256 bf16 = 8 MB
    unsigned int* ctr = (unsigned int*)(xb + (size_t)BB * MP * DD);  // 8 tickets, 64B apart

    norm_bf16<<<BB * MP / 4, 256, 0, stream>>>(x, xb, ctr, out);
    cl_mfma<<<GRID2, 256, 0, stream>>>(xb, deS, itS, ctr, out);
}